// Round 5
// baseline (122.972 us; speedup 1.0000x reference)
//
#include <hip/hip_runtime.h>
#include <math.h>

namespace {

constexpr int F = 10;
constexpr int H = 64;
constexpr int P = 6;

// ---- additive-path 1D LUT geometry (pair-packed: slot i = (v_i, v_{i+1})) ----
constexpr int   NLUT       = 1024;
constexpr float LUT_LO     = -14.5f;
constexpr float LUT_HI     = 6.5f;
constexpr float LUT_DX     = (LUT_HI - LUT_LO) / NLUT;
constexpr float LUT_INVDX  = NLUT / (LUT_HI - LUT_LO);
constexpr float LUT_POSMAX = (float)(NLUT - 2) + 0.999f;

// ---- pairwise-path 2D LUT geometry (pair-packed along jb) ----
constexpr int NB  = 256;
constexpr int N2D = P * NB * NB;                 // logical entries
constexpr float A_LO  = -6.5f;
constexpr float A_SPAN = 13.0f;
constexpr int PI[P] = {0, 0, 0, 0, 1, 2};
constexpr int PJ[P] = {4, 7, 9, 3, 4, 3};
constexpr float B_LO[P]   = {-14.5f, -6.5f, -6.5f, -6.5f, -14.5f, -6.5f};
constexpr float B_SPAN[P] = { 19.0f,  13.0f, 13.0f, 13.0f,  19.0f, 13.0f};
constexpr float POSMAX2   = (float)(NB - 1) - 0.001f;

// ws layout (floats):
//   [0, 2*N2D)                     : lut2 packed: slot(p,ia,jb) = (f(ia,jb), f(ia,jb+1))
//   [2*N2D, 2*N2D + 2*F*NLUT)      : lut1 packed: slot(f,i)     = (v_i, v_{i+1})
constexpr int WS_LUT1_OFF = 2 * N2D;
constexpr int WS_FLOATS   = 2 * N2D + 2 * F * NLUT;

// Exact-grade GELU: x * Phi(x), Phi via A&S 7.1.26 erfc (|err| <= 1.5e-7).
__device__ __forceinline__ float gelu_exact(float x) {
    const float kInvSqrt2 = 0.70710678118654752440f;
    float u = x * kInvSqrt2;
    float a = fabsf(u);
    float t = __builtin_amdgcn_rcpf(fmaf(0.3275911f, a, 1.0f));
    // coefficients pre-multiplied by 0.5
    float poly = t * fmaf(t, fmaf(t, fmaf(t, fmaf(t, 0.5307027145f,
                                                  -0.7265760135f),
                                           0.7107068705f),
                                   -0.142248368f),
                          0.127414796f);
    float e = __expf(-a * a);
    float half_erfc = poly * e;           // 0.5*erfc(|u|)
    float m = x * half_erfc;
    return (x >= 0.0f) ? (x - m) : m;
}

// ---------------- kernel 1: build pair-packed LUTs ------------------------
__global__ __launch_bounds__(256) void build_luts(
    const float* __restrict__ fw1,
    const float* __restrict__ fb1,
    const float* __restrict__ fw2,
    const float* __restrict__ fb2,
    const float* __restrict__ pw1,
    const float* __restrict__ pb1,
    const float* __restrict__ pw2,
    const float* __restrict__ pb2,
    float* __restrict__ ws)
{
    const int idx = blockIdx.x * blockDim.x + threadIdx.x;
    if (idx < N2D) {
        const int p   = idx >> 16;          // / (NB*NB)
        const int rem = idx & 0xFFFF;
        const int ia  = rem >> 8;
        const int jb  = rem & 0xFF;
        const bool f4 = (p == 0) | (p == 4);
        const float blo   = f4 ? -14.5f : -6.5f;
        const float bstep = (f4 ? 19.0f : 13.0f) / (float)(NB - 1);
        const float astep = A_SPAN / (float)(NB - 1);
        const float sa = fmaf((float)ia, astep, A_LO);
        const float sb = fmaf((float)jb, bstep, blo);
        const float* wa = pw1 + (p * 2 + 0) * H;
        const float* wb = pw1 + (p * 2 + 1) * H;
        const float* bb = pb1 + p * H;
        const float* w2 = pw2 + p * H;
        float acc = pb2[p];
        #pragma unroll 8
        for (int h = 0; h < H; ++h) {
            acc = fmaf(gelu_exact(fmaf(sa, wa[h], fmaf(sb, wb[h], bb[h]))),
                       w2[h], acc);
        }
        // pair-packed write: this value is .x of slot jb and .y of slot jb-1
        ws[2 * idx] = acc;
        if (jb > 0) ws[2 * idx - 1] = acc;
    } else if (idx < N2D + F * NLUT) {
        const int k = idx - N2D;
        const int f = k >> 10;
        const int i = k & 1023;
        const float s = LUT_LO + (float)i * LUT_DX;
        const float* w1 = fw1 + f * H;
        const float* b1 = fb1 + f * H;
        const float* w2 = fw2 + f * H;
        float acc = fb2[f];
        #pragma unroll 8
        for (int h = 0; h < H; ++h) {
            acc = fmaf(gelu_exact(fmaf(s, w1[h], b1[h])), w2[h], acc);
        }
        ws[WS_LUT1_OFF + 2 * k] = acc;
        if (i > 0) ws[WS_LUT1_OFF + 2 * k - 1] = acc;
    }
}

// bilinear lookup: two aligned float2 loads (rows ia, ia+1)
__device__ __forceinline__ float bilerp2(const float2* __restrict__ lutp,
                                         float sa, float sb,
                                         float ainv, float blo, float binv) {
    float pa = fminf(fmaxf((sa - A_LO) * ainv, 0.0f), POSMAX2);
    float pb = fminf(fmaxf((sb - blo) * binv, 0.0f), POSMAX2);
    int ia = (int)pa;
    int jb = (int)pb;
    float fa = pa - (float)ia;
    float fb = pb - (float)jb;
    float2 r0 = lutp[ia * NB + jb];
    float2 r1 = lutp[(ia + 1) * NB + jb];
    float v0 = fmaf(fb, r0.y - r0.x, r0.x);
    float v1 = fmaf(fb, r1.y - r1.x, r1.x);
    return fmaf(fa, v1 - v0, v0);
}

// ---------------- kernel 2: main kernel — all-LUT, no LDS, 1 row/thread ---
__global__ __launch_bounds__(256) void risk_lut2_kernel(
    const float* __restrict__ x,
    const float* __restrict__ raw_mean,
    const float* __restrict__ raw_std,
    const float* __restrict__ ws,
    float* __restrict__ out,
    int nrows)
{
    const float2* lut2 = reinterpret_cast<const float2*>(ws);
    const float2* lut1 = reinterpret_cast<const float2*>(ws + WS_LUT1_OFF);

    const int r = blockIdx.x * blockDim.x + threadIdx.x;
    if (r >= nrows) return;

    // ---- load 1 row: 10 floats = 5 aligned float2 (row base 40B -> 8B aligned)
    float v[F];
    {
        const float2* xp = reinterpret_cast<const float2*>(x + (size_t)r * F);
        float2 a = xp[0], b = xp[1], c = xp[2], d = xp[3], e = xp[4];
        v[0] = a.x; v[1] = a.y; v[2] = b.x; v[3] = b.y;
        v[4] = c.x; v[5] = c.y; v[6] = d.x; v[7] = d.y;
        v[8] = e.x; v[9] = e.y;
    }

    // ---- normalize (feature 4: log(clip(10x, 1e-6)))
    float s[F];
    #pragma unroll
    for (int f = 0; f < F; ++f) {
        float ra = v[f];
        if (f == 4) ra = __logf(fmaxf(ra * 10.0f, 1e-6f));
        s[f] = (ra - raw_mean[f]) / raw_std[f];
    }

    float acc = 0.0f;

    // ---- additive path: one float2 lerp per feature
    #pragma unroll
    for (int f = 0; f < F; ++f) {
        float pos = fminf(fmaxf(fmaf(s[f], LUT_INVDX, -LUT_LO * LUT_INVDX), 0.0f), LUT_POSMAX);
        int i = (int)pos;
        float fr = pos - (float)i;
        float2 c = lut1[f * NLUT + i];
        acc += fmaf(fr, c.y - c.x, c.x);
    }

    // ---- pairwise path: one bilerp (2 float2 loads) per pair
    constexpr float AINV = (float)(NB - 1) / A_SPAN;
    #pragma unroll
    for (int p = 0; p < P; ++p) {
        const float2* lutp = lut2 + p * NB * NB;
        const float binv = (float)(NB - 1) / B_SPAN[p];
        acc += bilerp2(lutp, s[PI[p]], s[PJ[p]], AINV, B_LO[p], binv);
    }

    out[r] = acc;
}

// ---------------- fallback: fully-computed kernel (if ws too small) -------
__global__ __launch_bounds__(256) void risk_full_kernel(
    const float* __restrict__ x,
    const float* __restrict__ raw_mean,
    const float* __restrict__ raw_std,
    const float* __restrict__ fw1,
    const float* __restrict__ fb1,
    const float* __restrict__ fw2,
    const float* __restrict__ fb2,
    const float* __restrict__ pw1,
    const float* __restrict__ pb1,
    const float* __restrict__ pw2,
    const float* __restrict__ pb2,
    float* __restrict__ out,
    int nrows)
{
    const int r = blockIdx.x * blockDim.x + threadIdx.x;
    if (r >= nrows) return;

    float s[F];
    #pragma unroll
    for (int f = 0; f < F; ++f) {
        float ra = x[(size_t)r * F + f];
        if (f == 4) ra = __logf(fmaxf(ra * 10.0f, 1e-6f));
        s[f] = (ra - raw_mean[f]) / raw_std[f];
    }

    float acc = 0.0f;
    #pragma unroll
    for (int f = 0; f < F; ++f) {
        const float* w1 = fw1 + f * H;
        const float* b1 = fb1 + f * H;
        const float* w2 = fw2 + f * H;
        float a0 = 0.0f;
        #pragma unroll 8
        for (int h = 0; h < H; ++h)
            a0 = fmaf(gelu_exact(fmaf(s[f], w1[h], b1[h])), w2[h], a0);
        acc += a0 + fb2[f];
    }
    #pragma unroll
    for (int p = 0; p < P; ++p) {
        const float* wa = pw1 + (p * 2 + 0) * H;
        const float* wb = pw1 + (p * 2 + 1) * H;
        const float* bb = pb1 + p * H;
        const float* w2 = pw2 + p * H;
        const float xa = s[PI[p]], xb = s[PJ[p]];
        float a0 = 0.0f;
        #pragma unroll 8
        for (int h = 0; h < H; ++h)
            a0 = fmaf(gelu_exact(fmaf(xa, wa[h], fmaf(xb, wb[h], bb[h]))), w2[h], a0);
        acc += a0 + pb2[p];
    }
    out[r] = acc;
}

} // namespace

extern "C" void kernel_launch(void* const* d_in, const int* in_sizes, int n_in,
                              void* d_out, int out_size, void* d_ws, size_t ws_size,
                              hipStream_t stream)
{
    const float* x        = (const float*)d_in[0];
    const float* raw_mean = (const float*)d_in[1];
    const float* raw_std  = (const float*)d_in[2];
    const float* fw1      = (const float*)d_in[3];
    const float* fb1      = (const float*)d_in[4];
    const float* fw2      = (const float*)d_in[5];
    const float* fb2      = (const float*)d_in[6];
    const float* pw1      = (const float*)d_in[7];
    const float* pb1      = (const float*)d_in[8];
    const float* pw2      = (const float*)d_in[9];
    const float* pb2      = (const float*)d_in[10];
    float* out = (float*)d_out;

    const int nrows = in_sizes[0] / F;           // 524288
    const int block = 256;
    const int grid = (nrows + block - 1) / block;   // 1 row/thread -> 2048 blocks

    const size_t lut_bytes = (size_t)WS_FLOATS * sizeof(float);
    if (ws_size >= lut_bytes) {
        float* lut = (float*)d_ws;
        const int n_entries = N2D + F * NLUT;
        build_luts<<<(n_entries + 255) / 256, 256, 0, stream>>>(
            fw1, fb1, fw2, fb2, pw1, pb1, pw2, pb2, lut);
        risk_lut2_kernel<<<grid, block, 0, stream>>>(
            x, raw_mean, raw_std, lut, out, nrows);
    } else {
        risk_full_kernel<<<grid, block, 0, stream>>>(
            x, raw_mean, raw_std, fw1, fb1, fw2, fb2,
            pw1, pb1, pw2, pb2, out, nrows);
    }
}

// Round 9
// 104.160 us; speedup vs baseline: 1.1806x; 1.1806x over previous
//
#include <hip/hip_runtime.h>
#include <math.h>

namespace {

constexpr int F = 10;
constexpr int H = 64;
constexpr int P = 6;

// ---- additive-path 1D LUT (pair-packed float2 slots) ----
constexpr int   NLUT       = 1024;
constexpr float LUT_LO     = -14.5f;
constexpr float LUT_HI     = 6.5f;
constexpr float LUT_DX     = (LUT_HI - LUT_LO) / NLUT;
constexpr float LUT_INVDX  = NLUT / (LUT_HI - LUT_LO);
constexpr float LUT_POSMAX = (float)(NLUT - 2) + 0.999f;

// ---- pairwise-path 2D LUT: NB x NB grid, quad-packed float4 slots ----
// slot(p,ia,jb) = (f(ia,jb), f(ia,jb+1), f(ia+1,jb), f(ia+1,jb+1))
constexpr int NB  = 128;
constexpr int N2D = P * NB * NB;                 // grid points (= threads)
constexpr float A_LO  = -6.5f;
constexpr float A_SPAN = 13.0f;
constexpr int PI[P] = {0, 0, 0, 0, 1, 2};
constexpr int PJ[P] = {4, 7, 9, 3, 4, 3};
constexpr float B_LO[P]   = {-14.5f, -6.5f, -6.5f, -6.5f, -14.5f, -6.5f};
constexpr float B_SPAN[P] = { 19.0f,  13.0f, 13.0f, 13.0f,  19.0f, 13.0f};
constexpr float POSMAX2   = (float)(NB - 1) - 0.001f;   // ia,jb <= NB-2

// ws layout (floats):
//   [0, 4*N2D)                  : lut2 quads (float4 per grid point)
//   [4*N2D, 4*N2D + 2*F*NLUT)   : lut1 pairs (float2 per slot)
constexpr int WS_LUT1_OFF = 4 * N2D;
constexpr int WS_FLOATS   = 4 * N2D + 2 * F * NLUT;

// Exact-grade GELU: x * Phi(x), Phi via A&S 7.1.26 erfc (|err| <= 1.5e-7).
__device__ __forceinline__ float gelu_exact(float x) {
    const float kInvSqrt2 = 0.70710678118654752440f;
    float u = x * kInvSqrt2;
    float a = fabsf(u);
    float t = __builtin_amdgcn_rcpf(fmaf(0.3275911f, a, 1.0f));
    // coefficients pre-multiplied by 0.5
    float poly = t * fmaf(t, fmaf(t, fmaf(t, fmaf(t, 0.5307027145f,
                                                  -0.7265760135f),
                                           0.7107068705f),
                                   -0.142248368f),
                          0.127414796f);
    float e = __expf(-a * a);
    float half_erfc = poly * e;           // 0.5*erfc(|u|)
    float m = x * half_erfc;
    return (x >= 0.0f) ? (x - m) : m;
}

// ---------------- kernel 1: build LUTs ------------------------------------
// Each 2D thread computes ONE grid value and scatters it into the <=4 quads
// that reference it. 4B stores, all within the quad-aligned table.
__global__ __launch_bounds__(256) void build_luts(
    const float* __restrict__ fw1,
    const float* __restrict__ fb1,
    const float* __restrict__ fw2,
    const float* __restrict__ fb2,
    const float* __restrict__ pw1,
    const float* __restrict__ pb1,
    const float* __restrict__ pw2,
    const float* __restrict__ pb2,
    float* __restrict__ ws)
{
    const int idx = blockIdx.x * blockDim.x + threadIdx.x;
    if (idx < N2D) {
        const int p   = idx / (NB * NB);
        const int rem = idx - p * (NB * NB);
        const int ia  = rem >> 7;           // / NB
        const int jb  = rem & (NB - 1);
        const bool f4 = (p == 0) | (p == 4);
        const float blo   = f4 ? -14.5f : -6.5f;
        const float bstep = (f4 ? 19.0f : 13.0f) / (float)(NB - 1);
        const float astep = A_SPAN / (float)(NB - 1);
        const float sa = fmaf((float)ia, astep, A_LO);
        const float sb = fmaf((float)jb, bstep, blo);
        const float* wa = pw1 + (p * 2 + 0) * H;
        const float* wb = pw1 + (p * 2 + 1) * H;
        const float* bb = pb1 + p * H;
        const float* w2 = pw2 + p * H;
        float acc = pb2[p];
        #pragma unroll 8
        for (int h = 0; h < H; ++h) {
            acc = fmaf(gelu_exact(fmaf(sa, wa[h], fmaf(sb, wb[h], bb[h]))),
                       w2[h], acc);
        }
        // scatter into the 4 quads that use grid point (ia, jb):
        // quad(ia ,jb )[0], quad(ia ,jb-1)[1], quad(ia-1,jb)[2], quad(ia-1,jb-1)[3]
        const int pbase = p * NB * NB;
        float* q = ws + 4 * (pbase + ia * NB + jb);
        q[0] = acc;
        if (jb > 0)           q[-4 + 1] = acc;
        if (ia > 0)           q[-4 * NB + 2] = acc;
        if (ia > 0 && jb > 0) q[-4 * (NB + 1) + 3] = acc;
    } else if (idx < N2D + F * NLUT) {
        const int k = idx - N2D;
        const int f = k >> 10;
        const int i = k & 1023;
        const float s = LUT_LO + (float)i * LUT_DX;
        const float* w1 = fw1 + f * H;
        const float* b1 = fb1 + f * H;
        const float* w2 = fw2 + f * H;
        float acc = fb2[f];
        #pragma unroll 8
        for (int h = 0; h < H; ++h) {
            acc = fmaf(gelu_exact(fmaf(s, w1[h], b1[h])), w2[h], acc);
        }
        ws[WS_LUT1_OFF + 2 * k] = acc;              // slot i, .x
        if (i > 0) ws[WS_LUT1_OFF + 2 * k - 1] = acc; // slot i-1, .y
    }
}

// bilinear lookup: ONE aligned float4 load
__device__ __forceinline__ float bilerp4(const float4* __restrict__ lutp,
                                         float sa, float sb,
                                         float ainv, float blo, float binv) {
    float pa = fminf(fmaxf((sa - A_LO) * ainv, 0.0f), POSMAX2);
    float pb = fminf(fmaxf((sb - blo) * binv, 0.0f), POSMAX2);
    int ia = (int)pa;
    int jb = (int)pb;
    float fa = pa - (float)ia;
    float fb = pb - (float)jb;
    float4 q = lutp[ia * NB + jb];
    float v0 = fmaf(fb, q.y - q.x, q.x);
    float v1 = fmaf(fb, q.w - q.z, q.z);
    return fmaf(fa, v1 - v0, v0);
}

// ---------------- kernel 2: main kernel — all-LUT, no LDS, 1 row/thread ---
__global__ __launch_bounds__(256) void risk_lut2_kernel(
    const float* __restrict__ x,
    const float* __restrict__ raw_mean,
    const float* __restrict__ raw_std,
    const float* __restrict__ ws,
    float* __restrict__ out,
    int nrows)
{
    const float4* lut2 = reinterpret_cast<const float4*>(ws);
    const float2* lut1 = reinterpret_cast<const float2*>(ws + WS_LUT1_OFF);

    const int r = blockIdx.x * blockDim.x + threadIdx.x;
    if (r >= nrows) return;

    // ---- load 1 row: 10 floats = 5 aligned float2
    float v[F];
    {
        const float2* xp = reinterpret_cast<const float2*>(x + (size_t)r * F);
        float2 a = xp[0], b = xp[1], c = xp[2], d = xp[3], e = xp[4];
        v[0] = a.x; v[1] = a.y; v[2] = b.x; v[3] = b.y;
        v[4] = c.x; v[5] = c.y; v[6] = d.x; v[7] = d.y;
        v[8] = e.x; v[9] = e.y;
    }

    // ---- normalize (feature 4: log(clip(10x, 1e-6)))
    float s[F];
    #pragma unroll
    for (int f = 0; f < F; ++f) {
        float ra = v[f];
        if (f == 4) ra = __logf(fmaxf(ra * 10.0f, 1e-6f));
        s[f] = (ra - raw_mean[f]) / raw_std[f];
    }

    float acc = 0.0f;

    // ---- additive path: one float2 lerp per feature
    #pragma unroll
    for (int f = 0; f < F; ++f) {
        float pos = fminf(fmaxf(fmaf(s[f], LUT_INVDX, -LUT_LO * LUT_INVDX), 0.0f), LUT_POSMAX);
        int i = (int)pos;
        float fr = pos - (float)i;
        float2 c = lut1[f * NLUT + i];
        acc += fmaf(fr, c.y - c.x, c.x);
    }

    // ---- pairwise path: one float4 bilerp per pair
    constexpr float AINV = (float)(NB - 1) / A_SPAN;
    #pragma unroll
    for (int p = 0; p < P; ++p) {
        const float4* lutp = lut2 + p * NB * NB;
        const float binv = (float)(NB - 1) / B_SPAN[p];
        acc += bilerp4(lutp, s[PI[p]], s[PJ[p]], AINV, B_LO[p], binv);
    }

    out[r] = acc;
}

// ---------------- fallback: fully-computed kernel (if ws too small) -------
__global__ __launch_bounds__(256) void risk_full_kernel(
    const float* __restrict__ x,
    const float* __restrict__ raw_mean,
    const float* __restrict__ raw_std,
    const float* __restrict__ fw1,
    const float* __restrict__ fb1,
    const float* __restrict__ fw2,
    const float* __restrict__ fb2,
    const float* __restrict__ pw1,
    const float* __restrict__ pb1,
    const float* __restrict__ pw2,
    const float* __restrict__ pb2,
    float* __restrict__ out,
    int nrows)
{
    const int r = blockIdx.x * blockDim.x + threadIdx.x;
    if (r >= nrows) return;

    float s[F];
    #pragma unroll
    for (int f = 0; f < F; ++f) {
        float ra = x[(size_t)r * F + f];
        if (f == 4) ra = __logf(fmaxf(ra * 10.0f, 1e-6f));
        s[f] = (ra - raw_mean[f]) / raw_std[f];
    }

    float acc = 0.0f;
    #pragma unroll
    for (int f = 0; f < F; ++f) {
        const float* w1 = fw1 + f * H;
        const float* b1 = fb1 + f * H;
        const float* w2 = fw2 + f * H;
        float a0 = 0.0f;
        #pragma unroll 8
        for (int h = 0; h < H; ++h)
            a0 = fmaf(gelu_exact(fmaf(s[f], w1[h], b1[h])), w2[h], a0);
        acc += a0 + fb2[f];
    }
    #pragma unroll
    for (int p = 0; p < P; ++p) {
        const float* wa = pw1 + (p * 2 + 0) * H;
        const float* wb = pw1 + (p * 2 + 1) * H;
        const float* bb = pb1 + p * H;
        const float* w2 = pw2 + p * H;
        const float xa = s[PI[p]], xb = s[PJ[p]];
        float a0 = 0.0f;
        #pragma unroll 8
        for (int h = 0; h < H; ++h)
            a0 = fmaf(gelu_exact(fmaf(xa, wa[h], fmaf(xb, wb[h], bb[h]))), w2[h], a0);
        acc += a0 + pb2[p];
    }
    out[r] = acc;
}

} // namespace

extern "C" void kernel_launch(void* const* d_in, const int* in_sizes, int n_in,
                              void* d_out, int out_size, void* d_ws, size_t ws_size,
                              hipStream_t stream)
{
    const float* x        = (const float*)d_in[0];
    const float* raw_mean = (const float*)d_in[1];
    const float* raw_std  = (const float*)d_in[2];
    const float* fw1      = (const float*)d_in[3];
    const float* fb1      = (const float*)d_in[4];
    const float* fw2      = (const float*)d_in[5];
    const float* fb2      = (const float*)d_in[6];
    const float* pw1      = (const float*)d_in[7];
    const float* pb1      = (const float*)d_in[8];
    const float* pw2      = (const float*)d_in[9];
    const float* pb2      = (const float*)d_in[10];
    float* out = (float*)d_out;

    const int nrows = in_sizes[0] / F;           // 524288
    const int block = 256;
    const int grid = (nrows + block - 1) / block;   // 1 row/thread -> 2048 blocks

    const size_t lut_bytes = (size_t)WS_FLOATS * sizeof(float);
    if (ws_size >= lut_bytes) {
        float* lut = (float*)d_ws;
        const int n_entries = N2D + F * NLUT;     // 98304 + 10240
        build_luts<<<(n_entries + 255) / 256, 256, 0, stream>>>(
            fw1, fb1, fw2, fb2, pw1, pb1, pw2, pb2, lut);
        risk_lut2_kernel<<<grid, block, 0, stream>>>(
            x, raw_mean, raw_std, lut, out, nrows);
    } else {
        risk_full_kernel<<<grid, block, 0, stream>>>(
            x, raw_mean, raw_std, fw1, fb1, fw2, fb2,
            pw1, pb1, pw2, pb2, out, nrows);
    }
}